// Round 1
// baseline (17788.510 us; speedup 1.0000x reference)
//
#include <hip/hip_runtime.h>

#define AD 128   // first spatial dim (H)
#define BD 128   // second spatial dim (W)
#define ZD 16    // third spatial dim (Z)
#define NVOX (AD*BD*ZD)   // 262144

__device__ __forceinline__ float leaky(float v) { return v > 0.f ? v : 0.01f * v; }

// Direct 3x3x3 conv, SAME padding. Input/out layout [C][A][B][Z] (Z fastest).
// Thread = one voxel; block computes OCT output channels (blockIdx.y tile).
// PREMUL: input value multiplied by (1 + prob[voxel]) (occ_in = x*prob + x).
// LEAKY: fused leaky_relu epilogue.
template<int IC, int OCT, bool PREMUL, bool LEAKY>
__global__ __launch_bounds__(256) void conv3x3(const float* __restrict__ in,
                                               const float* __restrict__ w,
                                               const float* __restrict__ bias,
                                               const float* __restrict__ prob,
                                               float* __restrict__ out) {
    const int p   = blockIdx.x * 256 + threadIdx.x;
    const int ocb = blockIdx.y * OCT;
    const int cz = p & (ZD - 1);
    const int bb = (p >> 4) & (BD - 1);
    const int aa = p >> 11;

    // Precompute per-tap validity mask (as multiplier) and clamped offsets.
    float pm[27];
    int   off[27];
    {
        int t = 0;
        #pragma unroll
        for (int da = -1; da <= 1; ++da)
        #pragma unroll
        for (int db = -1; db <= 1; ++db)
        #pragma unroll
        for (int dc = -1; dc <= 1; ++dc) {
            const bool valid = ((unsigned)(aa + da) < AD) &&
                               ((unsigned)(bb + db) < BD) &&
                               ((unsigned)(cz + dc) < ZD);
            const int o = da * (BD * ZD) + db * ZD + dc;
            off[t] = valid ? o : 0;            // clamp OOB addr to in-range
            float m = valid ? 1.f : 0.f;
            if (PREMUL) m = valid ? (1.f + prob[p + o]) : 0.f;
            pm[t] = m;
            ++t;
        }
    }

    float acc[OCT];
    #pragma unroll
    for (int o = 0; o < OCT; ++o) acc[o] = bias[ocb + o];

    for (int ic = 0; ic < IC; ++ic) {
        const float* ip = in + (size_t)ic * NVOX + p;
        float nb[27];
        #pragma unroll
        for (int t = 0; t < 27; ++t) nb[t] = ip[off[t]] * pm[t];
        const float* wp = w + (size_t)(ocb * IC + ic) * 27;   // w[oc][ic][27]
        #pragma unroll
        for (int t = 0; t < 27; ++t) {
            #pragma unroll
            for (int o = 0; o < OCT; ++o)
                acc[o] = fmaf(nb[t], wp[(size_t)o * IC * 27 + t], acc[o]);
        }
    }

    #pragma unroll
    for (int o = 0; o < OCT; ++o) {
        float v = acc[o];
        if (LEAKY) v = leaky(v);
        out[(size_t)(ocb + o) * NVOX + p] = v;
    }
}

// conv 64->2 (3x3x3) + occupancy mask: softmax(ch1)>0.5  <=>  logit1 > logit0
__global__ __launch_bounds__(256) void occ2_mask(const float* __restrict__ hbuf,
                                                 const float* __restrict__ w,
                                                 const float* __restrict__ bias,
                                                 unsigned char* __restrict__ mask) {
    const int p = blockIdx.x * 256 + threadIdx.x;
    const int cz = p & (ZD - 1);
    const int bb = (p >> 4) & (BD - 1);
    const int aa = p >> 11;
    float pm[27]; int off[27];
    {
        int t = 0;
        #pragma unroll
        for (int da = -1; da <= 1; ++da)
        #pragma unroll
        for (int db = -1; db <= 1; ++db)
        #pragma unroll
        for (int dc = -1; dc <= 1; ++dc) {
            const bool valid = ((unsigned)(aa + da) < AD) &&
                               ((unsigned)(bb + db) < BD) &&
                               ((unsigned)(cz + dc) < ZD);
            off[t] = valid ? (da * (BD * ZD) + db * ZD + dc) : 0;
            pm[t] = valid ? 1.f : 0.f;
            ++t;
        }
    }
    float a0 = bias[0], a1 = bias[1];
    for (int ic = 0; ic < 64; ++ic) {
        const float* ip = hbuf + (size_t)ic * NVOX + p;
        #pragma unroll
        for (int t = 0; t < 27; ++t) {
            const float v = ip[off[t]] * pm[t];
            a0 = fmaf(v, w[ic * 27 + t], a0);
            a1 = fmaf(v, w[64 * 27 + ic * 27 + t], a1);
        }
    }
    mask[p] = (a1 > a0) ? 1 : 0;
}

// Per-voxel MLP prior + masked select, in-place over x ([C][N] layout).
__global__ __launch_bounds__(256) void mlp_vox(float* __restrict__ x,
                                               const float* __restrict__ w1,
                                               const float* __restrict__ b1,
                                               const float* __restrict__ g,
                                               const float* __restrict__ beta,
                                               const float* __restrict__ w2,
                                               const float* __restrict__ b2,
                                               const unsigned char* __restrict__ mask) {
    const int p = blockIdx.x * 256 + threadIdx.x;
    float h[64];
    #pragma unroll
    for (int j = 0; j < 64; ++j) h[j] = b1[j];
    for (int c = 0; c < 128; ++c) {
        const float xv = x[(size_t)c * NVOX + p];
        #pragma unroll
        for (int j = 0; j < 64; ++j) h[j] = fmaf(xv, w1[c * 64 + j], h[j]);
    }
    // LayerNorm over 64 features (population var, eps 1e-5) + leaky
    float mu = 0.f;
    #pragma unroll
    for (int j = 0; j < 64; ++j) mu += h[j];
    mu *= (1.f / 64.f);
    float var = 0.f;
    #pragma unroll
    for (int j = 0; j < 64; ++j) { const float d = h[j] - mu; var = fmaf(d, d, var); }
    var *= (1.f / 64.f);
    const float rs = rsqrtf(var + 1e-5f);
    #pragma unroll
    for (int j = 0; j < 64; ++j) {
        const float v = (h[j] - mu) * rs * g[j] + beta[j];
        h[j] = leaky(v);
    }
    const bool m = mask[p] != 0;
    for (int c = 0; c < 128; ++c) {
        float pr = b2[c];
        #pragma unroll
        for (int j = 0; j < 64; ++j) pr = fmaf(h[j], w2[j * 128 + c], pr);
        const size_t idx = (size_t)c * NVOX + p;
        x[idx] = m ? x[idx] : pr;   // occupied keeps seed feature, else prior
    }
}

// 1x1x1 conv 64 -> 20 (SSC head), output [20][N] fp32.
__global__ __launch_bounds__(256) void ssc_head(const float* __restrict__ d,
                                                const float* __restrict__ w,
                                                const float* __restrict__ bias,
                                                float* __restrict__ out) {
    const int p = blockIdx.x * 256 + threadIdx.x;
    float acc[20];
    #pragma unroll
    for (int o = 0; o < 20; ++o) acc[o] = bias[o];
    for (int ic = 0; ic < 64; ++ic) {
        const float dv = d[(size_t)ic * NVOX + p];
        #pragma unroll
        for (int o = 0; o < 20; ++o) acc[o] = fmaf(dv, w[o * 64 + ic], acc[o]);
    }
    #pragma unroll
    for (int o = 0; o < 20; ++o) out[(size_t)o * NVOX + p] = acc[o];
}

extern "C" void kernel_launch(void* const* d_in, const int* in_sizes, int n_in,
                              void* d_out, int out_size, void* d_ws, size_t ws_size,
                              hipStream_t stream) {
    const float* x3d    = (const float*)d_in[0];
    const float* prob   = (const float*)d_in[1];
    const float* w_bot  = (const float*)d_in[2];
    const float* b_bot  = (const float*)d_in[3];
    const float* w_occ1 = (const float*)d_in[4];
    const float* b_occ1 = (const float*)d_in[5];
    const float* w_occ2 = (const float*)d_in[6];
    const float* b_occ2 = (const float*)d_in[7];
    const float* w_mlp1 = (const float*)d_in[8];
    const float* b_mlp1 = (const float*)d_in[9];
    const float* ln_g   = (const float*)d_in[10];
    const float* ln_b   = (const float*)d_in[11];
    const float* w_mlp2 = (const float*)d_in[12];
    const float* b_mlp2 = (const float*)d_in[13];
    const float* w_sdb  = (const float*)d_in[14];
    const float* b_sdb  = (const float*)d_in[15];
    const float* w_ssc  = (const float*)d_in[16];
    const float* b_ssc  = (const float*)d_in[17];

    float* ws = (float*)d_ws;
    float* x  = ws;                       // [128][N] fp32, 134.2 MB (vox in-place)
    float* hb = ws + (size_t)128 * NVOX;  // [64][N] fp32, 67.1 MB (occ_h, then d)
    unsigned char* mask = (unsigned char*)(ws + (size_t)192 * NVOX); // [N] bytes

    const dim3 blk(256);
    const int nb = NVOX / 256;  // 1024

    // 1) bottleneck conv 128->128
    conv3x3<128, 16, false, false><<<dim3(nb, 8), blk, 0, stream>>>(x3d, w_bot, b_bot, nullptr, x);
    // 2) occ conv1 128->64 on x*(1+prob), leaky
    conv3x3<128, 16, true, true><<<dim3(nb, 4), blk, 0, stream>>>(x, w_occ1, b_occ1, prob, hb);
    // 3) occ conv2 64->2 + mask
    occ2_mask<<<nb, blk, 0, stream>>>(hb, w_occ2, b_occ2, mask);
    // 4) MLP prior + masked select (vox overwrites x)
    mlp_vox<<<nb, blk, 0, stream>>>(x, w_mlp1, b_mlp1, ln_g, ln_b, w_mlp2, b_mlp2, mask);
    // 5) SDB conv 128->64 + leaky (d into hb)
    conv3x3<128, 16, false, true><<<dim3(nb, 4), blk, 0, stream>>>(x, w_sdb, b_sdb, nullptr, hb);
    // 6) SSC 1x1x1 conv 64->20 -> d_out
    ssc_head<<<nb, blk, 0, stream>>>(hb, w_ssc, b_ssc, (float*)d_out);
}

// Round 4
// 6399.430 us; speedup vs baseline: 2.7797x; 2.7797x over previous
//
#include <hip/hip_runtime.h>

#define AD 128
#define BDW 128
#define ZD 16
#define NVOX (AD*BDW*ZD)   // 262144
#define SLAB 16384         // 8 a-rows

typedef __attribute__((ext_vector_type(4))) float f32x4;
typedef __attribute__((ext_vector_type(8))) short bf16x8;

__device__ __forceinline__ float leaky(float v) { return v > 0.f ? v : 0.01f * v; }

__device__ __forceinline__ f32x4 mfma_bf(bf16x8 a, bf16x8 b, f32x4 c) {
    return __builtin_amdgcn_mfma_f32_16x16x32_bf16(a, b, c, 0, 0, 0);
}

// Exact 3-way bf16 split of fp32: v = h1 + h2 + h3 (bit-truncation, exact).
__device__ __forceinline__ void split3(float v, unsigned short& s1,
                                       unsigned short& s2, unsigned short& s3) {
    const unsigned u1 = __float_as_uint(v) & 0xFFFF0000u;
    const float r1 = v - __uint_as_float(u1);
    const unsigned u2 = __float_as_uint(r1) & 0xFFFF0000u;
    const float r2 = r1 - __uint_as_float(u2);
    s1 = (unsigned short)(u1 >> 16);
    s2 = (unsigned short)(u2 >> 16);
    s3 = (unsigned short)(__float_as_uint(r2) >> 16);  // r2 has <=8 sig bits: exact
}

// ---------------------------------------------------------------------------
// Weight 3-split: w[oc][128][27] fp32 -> 3 planes of [27][4][OC][32] bf16
__global__ __launch_bounds__(256) void wsplit3(const float* __restrict__ w,
                                               unsigned short* __restrict__ wp, int OC) {
    const int i = blockIdx.x * 256 + threadIdx.x;
    const int PS = OC * 3456;
    if (i >= PS) return;
    const int kp = i & 31;
    const int oc = (i >> 5) % OC;
    const int rest = (i >> 5) / OC;      // t*4+kb
    const int kb = rest & 3, t = rest >> 2;
    const float v = w[((size_t)oc * 128 + kb * 32 + kp) * 27 + t];
    unsigned short s1, s2, s3;
    split3(v, s1, s2, s3);
    wp[i] = s1; wp[i + PS] = s2; wp[i + 2 * PS] = s3;
}

// ---------------------------------------------------------------------------
// fp32-grade 3x3x3 conv via bf16 3-split MFMA (6 products per tile).
// src: [128][NVOX] f32. out: [OC][outN] f32. Block: 1 a-row x 4 b x 16 z = 64 vox.
// RING: 0 = full [OC][NVOX]; 1 = slab [OC][SLAB]; 2 = 3-slab ring [OC][3*SLAB].
template<int OC, bool PREMUL, bool LEAKY, int RING>
__global__ __launch_bounds__(256) void conv3s(const float* __restrict__ src,
                                              const float* __restrict__ prob,
                                              const unsigned short* __restrict__ W,
                                              const float* __restrict__ bias,
                                              float* __restrict__ out,
                                              int ablk_base) {
    __shared__ __align__(16) unsigned short smraw[3 * 324 * 40];   // 77760 B
    unsigned short* sm0 = smraw;
    unsigned short* sm1 = smraw + 12960;
    unsigned short* sm2 = smraw + 25920;

    const int tid = threadIdx.x;
    const int bx  = blockIdx.x;
    const int ablk = ablk_base + (bx >> 5);
    const int b0   = (bx & 31) * 4;
    const int vblock = ablk * 2048 + b0 * 16;

    const int w = tid >> 6, l = tid & 63;
    const int lo16 = l & 15, hi4 = l >> 4;
    constexpr int NF = (OC == 128) ? 2 : 1;
    constexpr int PS = OC * 3456;                 // weight plane stride (halfs)
    const int oc_off = w * (16 * NF);

    f32x4 acc0[4][NF], acc1[4][NF];
    const f32x4 z4 = {0.f, 0.f, 0.f, 0.f};
    #pragma unroll
    for (int mf = 0; mf < 4; ++mf)
        #pragma unroll
        for (int nf = 0; nf < NF; ++nf) { acc0[mf][nf] = z4; acc1[mf][nf] = z4; }

    #pragma unroll 1
    for (int kb = 0; kb < 4; ++kb) {
        __syncthreads();
        // stage 324 voxels x 32 ic, exact 3-way split
        for (int i = tid; i < 324 * 32; i += 256) {
            const int c = i / 324;
            const int v = i - c * 324;
            const int col = v / 18;
            const int zz  = v - col * 18;
            const int ta  = col / 6;
            const int bi  = col - ta * 6;
            const int a = ablk + ta - 1;
            const int b = b0 + bi - 1;
            const int z = zz - 1;
            float val = 0.f;
            if (((unsigned)a < 128u) && ((unsigned)b < 128u) && ((unsigned)z < 16u)) {
                const int q = a * 2048 + b * 16 + z;
                val = src[(size_t)(kb * 32 + c) * NVOX + q];
                if (PREMUL) val *= (1.f + prob[q]);
            }
            unsigned short s1, s2, s3;
            split3(val, s1, s2, s3);
            sm0[v * 40 + c] = s1;
            sm1[v * 40 + c] = s2;
            sm2[v * 40 + c] = s3;
        }
        __syncthreads();
        #pragma unroll 1
        for (int t = 0; t < 27; ++t) {
            const int ta = t / 9, tb = (t / 3) % 3, tz = t % 3;
            const size_t wb = ((size_t)(t * 4 + kb) * OC + oc_off + lo16) * 32 + hi4 * 8;
            bf16x8 b1[NF], b2[NF], b3[NF];
            #pragma unroll
            for (int nf = 0; nf < NF; ++nf) {
                b1[nf] = *(const bf16x8*)(W + wb + nf * 512);
                b2[nf] = *(const bf16x8*)(W + PS + wb + nf * 512);
                b3[nf] = *(const bf16x8*)(W + 2 * PS + wb + nf * 512);
            }
            #pragma unroll
            for (int mf = 0; mf < 4; ++mf) {
                const int v = (ta * 6 + mf + tb) * 18 + lo16 + tz;
                const bf16x8 a1 = *(const bf16x8*)(sm0 + v * 40 + hi4 * 8);
                const bf16x8 a2 = *(const bf16x8*)(sm1 + v * 40 + hi4 * 8);
                const bf16x8 a3 = *(const bf16x8*)(sm2 + v * 40 + hi4 * 8);
                #pragma unroll
                for (int nf = 0; nf < NF; ++nf) {
                    acc0[mf][nf] = mfma_bf(a1, b1[nf], acc0[mf][nf]);
                    acc1[mf][nf] = mfma_bf(a1, b2[nf], acc1[mf][nf]);
                    acc1[mf][nf] = mfma_bf(a2, b1[nf], acc1[mf][nf]);
                    acc1[mf][nf] = mfma_bf(a2, b2[nf], acc1[mf][nf]);
                    acc1[mf][nf] = mfma_bf(a1, b3[nf], acc1[mf][nf]);
                    acc1[mf][nf] = mfma_bf(a3, b1[nf], acc1[mf][nf]);
                }
            }
        }
    }

    // epilogue: combine accs + bias (+leaky), LDS transpose, [C][N] store
    __syncthreads();
    float* ldsT = (float*)smraw;     // [OC][65] floats
    #pragma unroll
    for (int mf = 0; mf < 4; ++mf)
        #pragma unroll
        for (int nf = 0; nf < NF; ++nf) {
            const int oc = oc_off + nf * 16 + lo16;
            #pragma unroll
            for (int r = 0; r < 4; ++r) {
                float vv = bias[oc] + acc0[mf][nf][r] + acc1[mf][nf][r];
                if (LEAKY) vv = leaky(vv);
                ldsT[oc * 65 + mf * 16 + hi4 * 4 + r] = vv;   // C/D: row=(l>>4)*4+r, col=l&15
            }
        }
    __syncthreads();
    int ocol;
    if (RING == 0)      ocol = vblock;
    else if (RING == 1) ocol = vblock & (SLAB - 1);
    else                ocol = ((ablk >> 3) % 3) * SLAB + (vblock & (SLAB - 1));
    const size_t outN = (RING == 0) ? (size_t)NVOX : ((RING == 1) ? (size_t)SLAB : (size_t)(3 * SLAB));
    for (int i = tid; i < OC * 64; i += 256) {
        const int oc = i >> 6, v = i & 63;
        out[(size_t)oc * outN + ocol + v] = ldsT[oc * 65 + v];
    }
}

// ---------------------------------------------------------------------------
// conv 64->2 (fp32 VALU) over occ_h ring + mask = logit1 > logit0
__global__ __launch_bounds__(256) void occ2_ring(const float* __restrict__ HR,
                                                 const float* __restrict__ w,
                                                 const float* __restrict__ bias,
                                                 unsigned char* __restrict__ mask,
                                                 int s) {
    const int pl = blockIdx.x * 256 + threadIdx.x;
    const int p = s * SLAB + pl;
    const int z = p & 15, b = (p >> 4) & 127, a = p >> 11;
    float a0 = bias[0], a1 = bias[1];
    #pragma unroll 1
    for (int t = 0; t < 27; ++t) {
        const int da = t / 9 - 1, db = (t / 3) % 3 - 1, dz = t % 3 - 1;
        if (((unsigned)(a + da) >= 128u) || ((unsigned)(b + db) >= 128u) ||
            ((unsigned)(z + dz) >= 16u)) continue;
        const int q = p + da * 2048 + db * 16 + dz;
        const int col = (((a + da) >> 3) % 3) * SLAB + (q & (SLAB - 1));
        #pragma unroll 8
        for (int ic = 0; ic < 64; ++ic) {
            const float v = HR[(size_t)ic * (3 * SLAB) + col];
            a0 = fmaf(v, w[ic * 27 + t], a0);
            a1 = fmaf(v, w[(64 + ic) * 27 + t], a1);
        }
    }
    mask[p] = (a1 > a0) ? 1 : 0;
}

// ---------------------------------------------------------------------------
// Per-voxel MLP prior + masked select, in-place over x ([128][N] f32)
__global__ __launch_bounds__(256) void mlp_vox(float* __restrict__ x,
                                               const float* __restrict__ w1,
                                               const float* __restrict__ b1,
                                               const float* __restrict__ g,
                                               const float* __restrict__ beta,
                                               const float* __restrict__ w2,
                                               const float* __restrict__ b2,
                                               const unsigned char* __restrict__ mask) {
    const int p = blockIdx.x * 256 + threadIdx.x;
    float h[64];
    #pragma unroll
    for (int j = 0; j < 64; ++j) h[j] = b1[j];
    #pragma unroll 1
    for (int c = 0; c < 128; ++c) {
        const float xv = x[(size_t)c * NVOX + p];
        #pragma unroll
        for (int j = 0; j < 64; ++j) h[j] = fmaf(xv, w1[c * 64 + j], h[j]);
    }
    float mu = 0.f;
    #pragma unroll
    for (int j = 0; j < 64; ++j) mu += h[j];
    mu *= (1.f / 64.f);
    float var = 0.f;
    #pragma unroll
    for (int j = 0; j < 64; ++j) { const float d = h[j] - mu; var = fmaf(d, d, var); }
    var *= (1.f / 64.f);
    const float rs = rsqrtf(var + 1e-5f);
    #pragma unroll
    for (int j = 0; j < 64; ++j) h[j] = leaky((h[j] - mu) * rs * g[j] + beta[j]);

    const bool m = mask[p] != 0;
    #pragma unroll 1
    for (int c = 0; c < 128; ++c) {
        float pr = b2[c];
        #pragma unroll
        for (int j = 0; j < 64; ++j) pr = fmaf(h[j], w2[j * 128 + c], pr);
        const size_t idx = (size_t)c * NVOX + p;
        x[idx] = m ? x[idx] : pr;
    }
}

// ---------------------------------------------------------------------------
// 1x1x1 conv 64->20 over D slab -> out [20][N] f32
__global__ __launch_bounds__(256) void ssc_slab(const float* __restrict__ D,
                                                const float* __restrict__ w,
                                                const float* __restrict__ bias,
                                                float* __restrict__ out, int s) {
    const int pl = blockIdx.x * 256 + threadIdx.x;
    const int p = s * SLAB + pl;
    float acc[20];
    #pragma unroll
    for (int o = 0; o < 20; ++o) acc[o] = bias[o];
    #pragma unroll 1
    for (int ic = 0; ic < 64; ++ic) {
        const float v = D[(size_t)ic * SLAB + pl];
        #pragma unroll
        for (int o = 0; o < 20; ++o) acc[o] = fmaf(v, w[o * 64 + ic], acc[o]);
    }
    #pragma unroll
    for (int o = 0; o < 20; ++o) out[(size_t)o * NVOX + p] = acc[o];
}

// ---------------------------------------------------------------------------
extern "C" void kernel_launch(void* const* d_in, const int* in_sizes, int n_in,
                              void* d_out, int out_size, void* d_ws, size_t ws_size,
                              hipStream_t stream) {
    const float* x3d    = (const float*)d_in[0];
    const float* prob   = (const float*)d_in[1];
    const float* w_bot  = (const float*)d_in[2];
    const float* b_bot  = (const float*)d_in[3];
    const float* w_occ1 = (const float*)d_in[4];
    const float* b_occ1 = (const float*)d_in[5];
    const float* w_occ2 = (const float*)d_in[6];
    const float* b_occ2 = (const float*)d_in[7];
    const float* w_mlp1 = (const float*)d_in[8];
    const float* b_mlp1 = (const float*)d_in[9];
    const float* ln_g   = (const float*)d_in[10];
    const float* ln_b   = (const float*)d_in[11];
    const float* w_mlp2 = (const float*)d_in[12];
    const float* b_mlp2 = (const float*)d_in[13];
    const float* w_sdb  = (const float*)d_in[14];
    const float* b_sdb  = (const float*)d_in[15];
    const float* w_ssc  = (const float*)d_in[16];
    const float* b_ssc  = (const float*)d_in[17];

    char* ws = (char*)d_ws;
    float* X32 = (float*)(ws);                      // [128][N] f32, 134.2 MB
    float* HR  = (float*)(ws + 134217728);          // [64][3*SLAB] f32 ring, 12.6 MB
    float* DS  = (float*)(ws + 146800640);          // [64][SLAB] f32 slab, 4.2 MB
    unsigned short* WB3 = (unsigned short*)(ws + 150994944);  // 3*442368*2 = 2654208 B
    unsigned short* W13 = (unsigned short*)(ws + 153649152);  // 3*221184*2 = 1327104 B
    unsigned short* WS3 = (unsigned short*)(ws + 154976256);  // 1327104 B
    unsigned char* mask = (unsigned char*)(ws + 156303360);   // 262144 B

    const dim3 blk(256);

    wsplit3<<<1728, blk, 0, stream>>>(w_bot,  WB3, 128);
    wsplit3<<<864,  blk, 0, stream>>>(w_occ1, W13, 64);
    wsplit3<<<864,  blk, 0, stream>>>(w_sdb,  WS3, 64);

    // 1) bottleneck conv 128->128 (fp32-grade) : x3d -> X32
    conv3s<128, false, false, 0><<<4096, blk, 0, stream>>>(x3d, nullptr, WB3, b_bot, X32, 0);

    // 2/3) occ conv1 (premul folded) per slab into ring; occ2+mask trails by 1 slab
    for (int s = 0; s < 16; ++s) {
        conv3s<64, true, true, 2><<<256, blk, 0, stream>>>(X32, prob, W13, b_occ1, HR, 8 * s);
        if (s >= 1) occ2_ring<<<64, blk, 0, stream>>>(HR, w_occ2, b_occ2, mask, s - 1);
    }
    occ2_ring<<<64, blk, 0, stream>>>(HR, w_occ2, b_occ2, mask, 15);

    // 4) MLP prior + masked select, in-place on X32
    mlp_vox<<<1024, blk, 0, stream>>>(X32, w_mlp1, b_mlp1, ln_g, ln_b, w_mlp2, b_mlp2, mask);

    // 5/6) SDB conv + SSC head per slab
    for (int s = 0; s < 16; ++s) {
        conv3s<64, false, true, 1><<<256, blk, 0, stream>>>(X32, nullptr, WS3, b_sdb, DS, 8 * s);
        ssc_slab<<<64, blk, 0, stream>>>(DS, w_ssc, b_ssc, (float*)d_out, s);
    }
}

// Round 5
// 2991.689 us; speedup vs baseline: 5.9460x; 2.1391x over previous
//
#include <hip/hip_runtime.h>

#define AD 128
#define BDW 128
#define ZD 16
#define NVOX (AD*BDW*ZD)   // 262144
#define SLAB 32768         // 16 a-rows per slab
#define NSLAB 8

typedef __attribute__((ext_vector_type(4))) float f32x4;
typedef __attribute__((ext_vector_type(8))) short bf16x8;
typedef __attribute__((ext_vector_type(4))) short s16x4;

__device__ __forceinline__ float leaky(float v) { return v > 0.f ? v : 0.01f * v; }

__device__ __forceinline__ f32x4 mfma_bf(bf16x8 a, bf16x8 b, f32x4 c) {
    return __builtin_amdgcn_mfma_f32_16x16x32_bf16(a, b, c, 0, 0, 0);
}

// Exact 3-way bf16 split of fp32: v = h1 + h2 + h3 (bit-truncation, exact).
__device__ __forceinline__ void split3(float v, unsigned short& s1,
                                       unsigned short& s2, unsigned short& s3) {
    const unsigned u1 = __float_as_uint(v) & 0xFFFF0000u;
    const float r1 = v - __uint_as_float(u1);
    const unsigned u2 = __float_as_uint(r1) & 0xFFFF0000u;
    const float r2 = r1 - __uint_as_float(u2);
    s1 = (unsigned short)(u1 >> 16);
    s2 = (unsigned short)(u2 >> 16);
    s3 = (unsigned short)(__float_as_uint(r2) >> 16);
}

// ---------------------------------------------------------------------------
// Weight 3-split: w[oc][128][27] fp32 -> 3 planes of [27][4][OC][32] bf16
__global__ __launch_bounds__(256) void wsplit3(const float* __restrict__ w,
                                               unsigned short* __restrict__ wp, int OC) {
    const int i = blockIdx.x * 256 + threadIdx.x;
    const int PS = OC * 3456;
    if (i >= PS) return;
    const int kp = i & 31;
    const int oc = (i >> 5) % OC;
    const int rest = (i >> 5) / OC;      // t*4+kb
    const int kb = rest & 3, t = rest >> 2;
    const float v = w[((size_t)oc * 128 + kb * 32 + kp) * 27 + t];
    unsigned short s1, s2, s3;
    split3(v, s1, s2, s3);
    wp[i] = s1; wp[i + PS] = s2; wp[i + 2 * PS] = s3;
}

// ---------------------------------------------------------------------------
// fp32-grade 3x3x3 conv via bf16-split MFMA.
// PROD=6: 3 planes (fp32-grade, mask path). PROD=3: 2 planes (post-mask path).
// src: [128][NVOX] f32. Block: 1 a-row x 4 b x 16 z = 64 vox; 4 waves.
// RING: 0 = full [OC][NVOX]; 2 = 3-slab ring [OC][3*SLAB].
// FUSESSC: epilogue computes 1x1 conv 64->20 into out[20][NVOX] directly.
// LDS swizzle: half-offset(v, c) = v*40 + ((cg ^ ((v>>3)&3))<<3) + (c&7), cg=c>>3.
template<int OC, int PROD, bool PREMUL, bool LEAKY, int RING, bool FUSESSC>
__global__ __launch_bounds__(256) void conv3s(const float* __restrict__ src,
                                              const float* __restrict__ prob,
                                              const unsigned short* __restrict__ W,
                                              const float* __restrict__ bias,
                                              float* __restrict__ out,
                                              const float* __restrict__ wssc,
                                              const float* __restrict__ bssc,
                                              int ablk_base) {
    constexpr int NPL = (PROD == 6) ? 3 : 2;
    __shared__ __align__(16) unsigned short smraw[NPL * 12960];
    unsigned short* sm0 = smraw;
    unsigned short* sm1 = smraw + 12960;
    unsigned short* sm2 = smraw + ((NPL == 3) ? 25920 : 12960);  // unused if NPL==2

    const int tid = threadIdx.x;
    // bijective XCD swizzle (gridDim.x divisible by 8 in all our launches)
    const int cpx = gridDim.x >> 3;
    const int bx = (blockIdx.x & 7) * cpx + (blockIdx.x >> 3);

    const int ablk = ablk_base + (bx >> 5);
    const int b0   = (bx & 31) * 4;
    const int vblock = ablk * 2048 + b0 * 16;

    const int w = tid >> 6, l = tid & 63;
    const int lo16 = l & 15, hi4 = l >> 4;
    constexpr int NF = (OC == 128) ? 2 : 1;
    constexpr int PS = OC * 3456;
    const int oc_off = w * (16 * NF);

    f32x4 acc0[4][NF], acc1[4][NF];
    const f32x4 z4 = {0.f, 0.f, 0.f, 0.f};
    #pragma unroll
    for (int mf = 0; mf < 4; ++mf)
        #pragma unroll
        for (int nf = 0; nf < NF; ++nf) { acc0[mf][nf] = z4; acc1[mf][nf] = z4; }

    #pragma unroll 1
    for (int kb = 0; kb < 4; ++kb) {
        __syncthreads();
        // stage 324 voxels x 32 ic as c-quads, split, swizzled b64 writes
        for (int i = tid; i < 2592; i += 256) {
            const int q4 = i / 324;               // c-quad index 0..7
            const int v  = i - q4 * 324;
            const int c0 = q4 * 4;
            const int col = v / 18;
            const int zz  = v - col * 18;
            const int ta  = col / 6;
            const int bi  = col - ta * 6;
            const int a = ablk + ta - 1;
            const int b = b0 + bi - 1;
            const int z = zz - 1;
            const bool ok = ((unsigned)a < 128u) && ((unsigned)b < 128u) && ((unsigned)z < 16u);
            const int q = a * 2048 + b * 16 + z;
            float pm = 1.f;
            if (PREMUL) pm = ok ? (1.f + prob[q]) : 1.f;
            s16x4 t1, t2, t3;
            #pragma unroll
            for (int j = 0; j < 4; ++j) {
                float f = ok ? src[(size_t)(kb * 32 + c0 + j) * NVOX + q] : 0.f;
                if (PREMUL) f *= pm;
                unsigned short s1, s2, s3;
                split3(f, s1, s2, s3);
                t1[j] = (short)s1; t2[j] = (short)s2; t3[j] = (short)s3;
            }
            const int off = v * 40 + (((q4 >> 1) ^ ((v >> 3) & 3)) << 3) + (q4 & 1) * 4;
            *(s16x4*)(sm0 + off) = t1;
            *(s16x4*)(sm1 + off) = t2;
            if (NPL == 3) *(s16x4*)(sm2 + off) = t3;
        }
        __syncthreads();
        #pragma unroll 1
        for (int t = 0; t < 27; ++t) {
            const int ta = t / 9, tb = (t / 3) % 3, tz = t % 3;
            const size_t wb = ((size_t)(t * 4 + kb) * OC + oc_off + lo16) * 32 + hi4 * 8;
            bf16x8 b1[NF], b2[NF], b3[NF];
            #pragma unroll
            for (int nf = 0; nf < NF; ++nf) {
                b1[nf] = *(const bf16x8*)(W + wb + nf * 512);
                b2[nf] = *(const bf16x8*)(W + PS + wb + nf * 512);
                if (PROD == 6) b3[nf] = *(const bf16x8*)(W + 2 * PS + wb + nf * 512);
            }
            #pragma unroll
            for (int mf = 0; mf < 4; ++mf) {
                const int v = (ta * 6 + mf + tb) * 18 + lo16 + tz;
                const int ao = v * 40 + ((hi4 ^ ((v >> 3) & 3)) << 3);
                const bf16x8 a1 = *(const bf16x8*)(sm0 + ao);
                const bf16x8 a2 = *(const bf16x8*)(sm1 + ao);
                #pragma unroll
                for (int nf = 0; nf < NF; ++nf) {
                    acc0[mf][nf] = mfma_bf(a1, b1[nf], acc0[mf][nf]);
                    acc1[mf][nf] = mfma_bf(a1, b2[nf], acc1[mf][nf]);
                    acc1[mf][nf] = mfma_bf(a2, b1[nf], acc1[mf][nf]);
                }
                if (PROD == 6) {
                    const bf16x8 a3 = *(const bf16x8*)(sm2 + ao);
                    #pragma unroll
                    for (int nf = 0; nf < NF; ++nf) {
                        acc1[mf][nf] = mfma_bf(a2, b2[nf], acc1[mf][nf]);
                        acc1[mf][nf] = mfma_bf(a1, b3[nf], acc1[mf][nf]);
                        acc1[mf][nf] = mfma_bf(a3, b1[nf], acc1[mf][nf]);
                    }
                }
            }
        }
    }

    // epilogue: combine accs + bias (+leaky) -> ldsT[oc][65]
    __syncthreads();
    float* ldsT = (float*)smraw;
    #pragma unroll
    for (int mf = 0; mf < 4; ++mf)
        #pragma unroll
        for (int nf = 0; nf < NF; ++nf) {
            const int oc = oc_off + nf * 16 + lo16;
            #pragma unroll
            for (int r = 0; r < 4; ++r) {
                float vv = bias[oc] + acc0[mf][nf][r] + acc1[mf][nf][r];
                if (LEAKY) vv = leaky(vv);
                ldsT[oc * 65 + mf * 16 + hi4 * 4 + r] = vv;   // C/D: row=(l>>4)*4+r, col=l&15
            }
        }
    __syncthreads();
    if (FUSESSC) {
        // 1x1 conv 64->20 from LDS, write [20][NVOX]
        for (int i = tid; i < 20 * 64; i += 256) {
            const int v = i & 63;
            const int o = i >> 6;           // wave-uniform
            float acc = bssc[o];
            #pragma unroll
            for (int ic = 0; ic < 64; ++ic)
                acc = fmaf(ldsT[ic * 65 + v], wssc[o * 64 + ic], acc);
            out[(size_t)o * NVOX + vblock + v] = acc;
        }
    } else {
        int ocol;
        if (RING == 0) ocol = vblock;
        else           ocol = ((ablk >> 4) % 3) * SLAB + (vblock & (SLAB - 1));
        const size_t outN = (RING == 0) ? (size_t)NVOX : (size_t)(3 * SLAB);
        for (int i = tid; i < OC * 64; i += 256) {
            const int oc = i >> 6, v = i & 63;
            out[(size_t)oc * outN + ocol + v] = ldsT[oc * 65 + v];
        }
    }
}

// ---------------------------------------------------------------------------
// conv 64->2 over occ_h ring, ic-parallel (32 vox x 8 ic-groups per block),
// LDS reduce + mask = logit1 > logit0
__global__ __launch_bounds__(256) void occ2p(const float* __restrict__ HR,
                                             const float* __restrict__ w,
                                             const float* __restrict__ bias,
                                             unsigned char* __restrict__ mask,
                                             int s) {
    __shared__ float wl[3456];
    __shared__ float r0[8][33], r1[8][33];
    const int tid = threadIdx.x;
    for (int i = tid; i < 3456; i += 256) wl[i] = w[i];
    const int v32 = tid & 31, g = tid >> 5;
    const int pl = blockIdx.x * 32 + v32;
    const int p = s * SLAB + pl;
    const int z = p & 15, b = (p >> 4) & 127, a = p >> 11;
    __syncthreads();
    float a0 = 0.f, a1 = 0.f;
    #pragma unroll 1
    for (int t = 0; t < 27; ++t) {
        const int da = t / 9 - 1, db = (t / 3) % 3 - 1, dz = t % 3 - 1;
        if (((unsigned)(a + da) >= 128u) || ((unsigned)(b + db) >= 128u) ||
            ((unsigned)(z + dz) >= 16u)) continue;
        const int q = p + da * 2048 + db * 16 + dz;
        const int col = (((a + da) >> 4) % 3) * SLAB + (q & (SLAB - 1));
        #pragma unroll
        for (int j = 0; j < 8; ++j) {
            const int ic = g * 8 + j;
            const float v = HR[(size_t)ic * (3 * SLAB) + col];
            a0 = fmaf(v, wl[ic * 27 + t], a0);
            a1 = fmaf(v, wl[1728 + ic * 27 + t], a1);
        }
    }
    r0[g][v32] = a0; r1[g][v32] = a1;
    __syncthreads();
    if (g == 0) {
        float t0 = bias[0], t1 = bias[1];
        #pragma unroll
        for (int k = 0; k < 8; ++k) { t0 += r0[k][v32]; t1 += r1[k][v32]; }
        mask[p] = (t1 > t0) ? 1 : 0;
    }
}

// ---------------------------------------------------------------------------
// Per-voxel MLP prior + masked select, in-place over x ([128][N] f32)
__global__ __launch_bounds__(256) void mlp_vox(float* __restrict__ x,
                                               const float* __restrict__ w1,
                                               const float* __restrict__ b1,
                                               const float* __restrict__ g,
                                               const float* __restrict__ beta,
                                               const float* __restrict__ w2,
                                               const float* __restrict__ b2,
                                               const unsigned char* __restrict__ mask) {
    const int p = blockIdx.x * 256 + threadIdx.x;
    float h[64];
    #pragma unroll
    for (int j = 0; j < 64; ++j) h[j] = b1[j];
    #pragma unroll 1
    for (int c = 0; c < 128; ++c) {
        const float xv = x[(size_t)c * NVOX + p];
        #pragma unroll
        for (int j = 0; j < 64; ++j) h[j] = fmaf(xv, w1[c * 64 + j], h[j]);
    }
    float mu = 0.f;
    #pragma unroll
    for (int j = 0; j < 64; ++j) mu += h[j];
    mu *= (1.f / 64.f);
    float var = 0.f;
    #pragma unroll
    for (int j = 0; j < 64; ++j) { const float d = h[j] - mu; var = fmaf(d, d, var); }
    var *= (1.f / 64.f);
    const float rs = rsqrtf(var + 1e-5f);
    #pragma unroll
    for (int j = 0; j < 64; ++j) h[j] = leaky((h[j] - mu) * rs * g[j] + beta[j]);

    const bool m = mask[p] != 0;
    #pragma unroll 1
    for (int c = 0; c < 128; ++c) {
        float pr = b2[c];
        #pragma unroll
        for (int j = 0; j < 64; ++j) pr = fmaf(h[j], w2[j * 128 + c], pr);
        const size_t idx = (size_t)c * NVOX + p;
        x[idx] = m ? x[idx] : pr;
    }
}

// ---------------------------------------------------------------------------
extern "C" void kernel_launch(void* const* d_in, const int* in_sizes, int n_in,
                              void* d_out, int out_size, void* d_ws, size_t ws_size,
                              hipStream_t stream) {
    const float* x3d    = (const float*)d_in[0];
    const float* prob   = (const float*)d_in[1];
    const float* w_bot  = (const float*)d_in[2];
    const float* b_bot  = (const float*)d_in[3];
    const float* w_occ1 = (const float*)d_in[4];
    const float* b_occ1 = (const float*)d_in[5];
    const float* w_occ2 = (const float*)d_in[6];
    const float* b_occ2 = (const float*)d_in[7];
    const float* w_mlp1 = (const float*)d_in[8];
    const float* b_mlp1 = (const float*)d_in[9];
    const float* ln_g   = (const float*)d_in[10];
    const float* ln_b   = (const float*)d_in[11];
    const float* w_mlp2 = (const float*)d_in[12];
    const float* b_mlp2 = (const float*)d_in[13];
    const float* w_sdb  = (const float*)d_in[14];
    const float* b_sdb  = (const float*)d_in[15];
    const float* w_ssc  = (const float*)d_in[16];
    const float* b_ssc  = (const float*)d_in[17];

    char* ws = (char*)d_ws;
    float* X32 = (float*)(ws);                                 // [128][N] f32, 134.2 MB
    float* HR  = (float*)(ws + 134217728);                     // [64][3*SLAB] f32 ring, 25.2 MB
    unsigned short* WB3 = (unsigned short*)(ws + 159383552);   // 2654208 B
    unsigned short* W13 = (unsigned short*)(ws + 162037760);   // 1327104 B
    unsigned short* WS3 = (unsigned short*)(ws + 163364864);   // 1327104 B
    unsigned char* mask = (unsigned char*)(ws + 164691968);    // 262144 B

    const dim3 blk(256);

    wsplit3<<<1728, blk, 0, stream>>>(w_bot,  WB3, 128);
    wsplit3<<<864,  blk, 0, stream>>>(w_occ1, W13, 64);
    wsplit3<<<864,  blk, 0, stream>>>(w_sdb,  WS3, 64);

    // 1) bottleneck conv 128->128 (6-product) : x3d -> X32
    conv3s<128, 6, false, false, 0, false><<<4096, blk, 0, stream>>>(
        x3d, nullptr, WB3, b_bot, X32, nullptr, nullptr, 0);

    // 2/3) occ conv1 (premul folded, 6-product) per slab into ring; occ2 trails
    for (int s = 0; s < NSLAB; ++s) {
        conv3s<64, 6, true, true, 2, false><<<512, blk, 0, stream>>>(
            X32, prob, W13, b_occ1, HR, nullptr, nullptr, 16 * s);
        if (s >= 1) occ2p<<<1024, blk, 0, stream>>>(HR, w_occ2, b_occ2, mask, s - 1);
    }
    occ2p<<<1024, blk, 0, stream>>>(HR, w_occ2, b_occ2, mask, NSLAB - 1);

    // 4) MLP prior + masked select, in-place on X32
    mlp_vox<<<1024, blk, 0, stream>>>(X32, w_mlp1, b_mlp1, ln_g, ln_b, w_mlp2, b_mlp2, mask);

    // 5/6) SDB conv (3-product) + fused SSC head -> d_out [20][N] f32
    conv3s<64, 3, false, true, 0, true><<<4096, blk, 0, stream>>>(
        X32, nullptr, WS3, b_sdb, (float*)d_out, w_ssc, b_ssc, 0);
}

// Round 6
// 2554.156 us; speedup vs baseline: 6.9645x; 1.1713x over previous
//
#include <hip/hip_runtime.h>

#define AD 128
#define BDW 128
#define ZD 16
#define NVOX (AD*BDW*ZD)   // 262144
#define SLAB 32768         // 16 a-rows per slab
#define NSLAB 8

typedef __attribute__((ext_vector_type(4))) float f32x4;
typedef __attribute__((ext_vector_type(8))) short bf16x8;
typedef __attribute__((ext_vector_type(4))) short s16x4;

__device__ __forceinline__ float leaky(float v) { return v > 0.f ? v : 0.01f * v; }

__device__ __forceinline__ f32x4 mfma_bf(bf16x8 a, bf16x8 b, f32x4 c) {
    return __builtin_amdgcn_mfma_f32_16x16x32_bf16(a, b, c, 0, 0, 0);
}

// Exact 3-way bf16 split of fp32: v = h1 + h2 + h3 (bit-truncation, exact).
__device__ __forceinline__ void split3(float v, unsigned short& s1,
                                       unsigned short& s2, unsigned short& s3) {
    const unsigned u1 = __float_as_uint(v) & 0xFFFF0000u;
    const float r1 = v - __uint_as_float(u1);
    const unsigned u2 = __float_as_uint(r1) & 0xFFFF0000u;
    const float r2 = r1 - __uint_as_float(u2);
    s1 = (unsigned short)(u1 >> 16);
    s2 = (unsigned short)(u2 >> 16);
    s3 = (unsigned short)(__float_as_uint(r2) >> 16);
}

// LDS A-plane addressing (halves): row stride 32, XOR swizzle on 16B slots.
// offH(v, chunk) = ((v*32 + chunk*8) ^ ((v&7)<<3))   [chunk = 16B chunk 0..3]
__device__ __forceinline__ int lds_a_off(int v, int chunk) {
    return ((v << 5) + (chunk << 3)) ^ ((v & 7) << 3);
}

// ---------------------------------------------------------------------------
// Weight 3-split: w[oc][128][27] fp32 -> 3 planes of [27][4][OC][32] bf16
__global__ __launch_bounds__(256) void wsplit3(const float* __restrict__ w,
                                               unsigned short* __restrict__ wp, int OC) {
    const int i = blockIdx.x * 256 + threadIdx.x;
    const int PS = OC * 3456;
    if (i >= PS) return;
    const int kp = i & 31;
    const int oc = (i >> 5) % OC;
    const int rest = (i >> 5) / OC;      // t*4+kb
    const int kb = rest & 3, t = rest >> 2;
    const float v = w[((size_t)oc * 128 + kb * 32 + kp) * 27 + t];
    unsigned short s1, s2, s3;
    split3(v, s1, s2, s3);
    wp[i] = s1; wp[i + PS] = s2; wp[i + 2 * PS] = s3;
}

// ---------------------------------------------------------------------------
// fp32-grade 3x3x3 conv via bf16-split MFMA.
// PROD=6: 3 planes (fp32-grade, mask path). PROD=3: 2 planes (post-mask path).
// src: [128][NVOX] f32. Block: 1 a-row x 4 b x 16 z = 64 vox; 4 waves.
// RING: 0 = full [OC][NVOX]; 2 = 3-slab ring [OC][3*SLAB].
// FUSESSC: epilogue computes 1x1 conv 64->20 into out[20][NVOX] directly.
// Pipeline: per kb, global loads for kb+1 issued before the 27-tap MFMA loop
// (T14 issue-early / write-late); LDS staging swizzled per G4/T2.
template<int OC, int PROD, bool PREMUL, bool LEAKY, int RING, bool FUSESSC>
__global__ __launch_bounds__(256, 2) void conv3s(const float* __restrict__ src,
                                              const float* __restrict__ prob,
                                              const unsigned short* __restrict__ W,
                                              const float* __restrict__ bias,
                                              float* __restrict__ out,
                                              const float* __restrict__ wssc,
                                              const float* __restrict__ bssc,
                                              int ablk_base) {
    constexpr int NPL = (PROD == 6) ? 3 : 2;
    constexpr int PLH = 324 * 32;                  // plane size in halves
    __shared__ __align__(16) unsigned short smraw[NPL * PLH];
    unsigned short* sm0 = smraw;
    unsigned short* sm1 = smraw + PLH;
    unsigned short* sm2 = smraw + (NPL - 1) * PLH; // ==sm1 when NPL==2 (unused)

    const int tid = threadIdx.x;
    // bijective XCD swizzle (gridDim.x divisible by 8 in all our launches)
    const int cpx = gridDim.x >> 3;
    const int bx = (blockIdx.x & 7) * cpx + (blockIdx.x >> 3);

    const int ablk = ablk_base + (bx >> 5);
    const int b0   = (bx & 31) * 4;
    const int vblock = ablk * 2048 + b0 * 16;

    const int w = tid >> 6, l = tid & 63;
    const int lo16 = l & 15, hi4 = l >> 4;
    constexpr int NF = (OC == 128) ? 2 : 1;
    constexpr int PS = OC * 3456;
    const int oc_off = w * (16 * NF);

    f32x4 acc0[4][NF], acc1[4][NF];
    const f32x4 z4 = {0.f, 0.f, 0.f, 0.f};
    #pragma unroll
    for (int mf = 0; mf < 4; ++mf)
        #pragma unroll
        for (int nf = 0; nf < NF; ++nf) { acc0[mf][nf] = z4; acc1[mf][nf] = z4; }

    // ---- prefetch registers (issue-early / write-late pipeline) ----
    float pf[11][4];
    float pfpm[11];

    #define PREFETCH(KB)                                                          \
        _Pragma("unroll")                                                         \
        for (int it = 0; it < 11; ++it) {                                         \
            const int i = tid + it * 256;                                         \
            float v0 = 0.f, v1 = 0.f, v2 = 0.f, v3 = 0.f, pm = 1.f;               \
            if (i < 2592) {                                                       \
                const int q4 = i / 324;                                           \
                const int v  = i - q4 * 324;                                      \
                const int col = v / 18;                                           \
                const int zz  = v - col * 18;                                     \
                const int ta  = col / 6;                                          \
                const int bi  = col - ta * 6;                                     \
                const int a = ablk + ta - 1;                                      \
                const int b = b0 + bi - 1;                                        \
                const int z = zz - 1;                                             \
                if (((unsigned)a < 128u) && ((unsigned)b < 128u) &&               \
                    ((unsigned)z < 16u)) {                                        \
                    const int q = a * 2048 + b * 16 + z;                          \
                    const float* sp = src + (size_t)((KB) * 32 + q4 * 4) * NVOX + q; \
                    v0 = sp[0]; v1 = sp[(size_t)NVOX];                            \
                    v2 = sp[(size_t)2 * NVOX]; v3 = sp[(size_t)3 * NVOX];         \
                    if (PREMUL) pm = 1.f + prob[q];                               \
                }                                                                 \
            }                                                                     \
            pf[it][0] = v0; pf[it][1] = v1; pf[it][2] = v2; pf[it][3] = v3;       \
            if (PREMUL) pfpm[it] = pm;                                            \
        }

    PREFETCH(0)

    #pragma unroll 1
    for (int kb = 0; kb < 4; ++kb) {
        __syncthreads();
        // write-late: split3 + swizzled ds_write of the prefetched tile
        #pragma unroll
        for (int it = 0; it < 11; ++it) {
            const int i = tid + it * 256;
            if (i < 2592) {
                const int q4 = i / 324;
                const int v  = i - q4 * 324;
                s16x4 t1, t2, t3;
                #pragma unroll
                for (int j = 0; j < 4; ++j) {
                    float f = pf[it][j];
                    if (PREMUL) f *= pfpm[it];
                    unsigned short s1, s2, s3;
                    split3(f, s1, s2, s3);
                    t1[j] = (short)s1; t2[j] = (short)s2; t3[j] = (short)s3;
                }
                const int off = lds_a_off(v, q4 >> 1) + (q4 & 1) * 4;
                *(s16x4*)(sm0 + off) = t1;
                *(s16x4*)(sm1 + off) = t2;
                if (NPL == 3) *(s16x4*)(sm2 + off) = t3;
            }
        }
        if (kb < 3) PREFETCH(kb + 1)
        __syncthreads();

        #pragma unroll 1
        for (int t = 0; t < 27; ++t) {
            const int ta = t / 9, tb = (t / 3) % 3, tz = t % 3;
            const size_t wb = ((size_t)(t * 4 + kb) * OC + oc_off + lo16) * 32 + hi4 * 8;
            bf16x8 b1[NF], b2[NF], b3[NF];
            #pragma unroll
            for (int nf = 0; nf < NF; ++nf) {
                b1[nf] = *(const bf16x8*)(W + wb + nf * 512);
                b2[nf] = *(const bf16x8*)(W + PS + wb + nf * 512);
                if (PROD == 6) b3[nf] = *(const bf16x8*)(W + 2 * PS + wb + nf * 512);
            }
            #pragma unroll
            for (int mf = 0; mf < 4; ++mf) {
                const int v = (ta * 6 + mf + tb) * 18 + lo16 + tz;
                const int ao = lds_a_off(v, hi4);
                const bf16x8 a1 = *(const bf16x8*)(sm0 + ao);
                const bf16x8 a2 = *(const bf16x8*)(sm1 + ao);
                #pragma unroll
                for (int nf = 0; nf < NF; ++nf) {
                    acc0[mf][nf] = mfma_bf(a1, b1[nf], acc0[mf][nf]);
                    acc1[mf][nf] = mfma_bf(a1, b2[nf], acc1[mf][nf]);
                    acc1[mf][nf] = mfma_bf(a2, b1[nf], acc1[mf][nf]);
                }
                if (PROD == 6) {
                    const bf16x8 a3 = *(const bf16x8*)(sm2 + ao);
                    #pragma unroll
                    for (int nf = 0; nf < NF; ++nf) {
                        acc1[mf][nf] = mfma_bf(a2, b2[nf], acc1[mf][nf]);
                        acc1[mf][nf] = mfma_bf(a1, b3[nf], acc1[mf][nf]);
                        acc1[mf][nf] = mfma_bf(a3, b1[nf], acc1[mf][nf]);
                    }
                }
            }
        }
    }
    #undef PREFETCH

    // epilogue: combine accs + bias (+leaky) -> ldsT[oc][65]
    __syncthreads();
    float* ldsT = (float*)smraw;
    #pragma unroll
    for (int mf = 0; mf < 4; ++mf)
        #pragma unroll
        for (int nf = 0; nf < NF; ++nf) {
            const int oc = oc_off + nf * 16 + lo16;
            #pragma unroll
            for (int r = 0; r < 4; ++r) {
                float vv = bias[oc] + acc0[mf][nf][r] + acc1[mf][nf][r];
                if (LEAKY) vv = leaky(vv);
                ldsT[oc * 65 + mf * 16 + hi4 * 4 + r] = vv;   // C/D: row=(l>>4)*4+r, col=l&15
            }
        }
    __syncthreads();
    if (FUSESSC) {
        // 1x1 conv 64->20 from LDS, write [20][NVOX]
        for (int i = tid; i < 20 * 64; i += 256) {
            const int v = i & 63;
            const int o = i >> 6;           // wave-uniform
            float acc = bssc[o];
            #pragma unroll
            for (int ic = 0; ic < 64; ++ic)
                acc = fmaf(ldsT[ic * 65 + v], wssc[o * 64 + ic], acc);
            out[(size_t)o * NVOX + vblock + v] = acc;
        }
    } else {
        int ocol;
        if (RING == 0) ocol = vblock;
        else           ocol = ((ablk >> 4) % 3) * SLAB + (vblock & (SLAB - 1));
        const size_t outN = (RING == 0) ? (size_t)NVOX : (size_t)(3 * SLAB);
        for (int i = tid; i < OC * 64; i += 256) {
            const int oc = i >> 6, v = i & 63;
            out[(size_t)oc * outN + ocol + v] = ldsT[oc * 65 + v];
        }
    }
}

// ---------------------------------------------------------------------------
// conv 64->2 over occ_h ring, ic-parallel (32 vox x 8 ic-groups per block),
// LDS reduce + mask = logit1 > logit0
__global__ __launch_bounds__(256) void occ2p(const float* __restrict__ HR,
                                             const float* __restrict__ w,
                                             const float* __restrict__ bias,
                                             unsigned char* __restrict__ mask,
                                             int s) {
    __shared__ float wl[3456];
    __shared__ float r0[8][33], r1[8][33];
    const int tid = threadIdx.x;
    for (int i = tid; i < 3456; i += 256) wl[i] = w[i];
    const int v32 = tid & 31, g = tid >> 5;
    const int pl = blockIdx.x * 32 + v32;
    const int p = s * SLAB + pl;
    const int z = p & 15, b = (p >> 4) & 127, a = p >> 11;
    __syncthreads();
    float a0 = 0.f, a1 = 0.f;
    #pragma unroll 1
    for (int t = 0; t < 27; ++t) {
        const int da = t / 9 - 1, db = (t / 3) % 3 - 1, dz = t % 3 - 1;
        if (((unsigned)(a + da) >= 128u) || ((unsigned)(b + db) >= 128u) ||
            ((unsigned)(z + dz) >= 16u)) continue;
        const int q = p + da * 2048 + db * 16 + dz;
        const int col = (((a + da) >> 4) % 3) * SLAB + (q & (SLAB - 1));
        #pragma unroll
        for (int j = 0; j < 8; ++j) {
            const int ic = g * 8 + j;
            const float v = HR[(size_t)ic * (3 * SLAB) + col];
            a0 = fmaf(v, wl[ic * 27 + t], a0);
            a1 = fmaf(v, wl[1728 + ic * 27 + t], a1);
        }
    }
    r0[g][v32] = a0; r1[g][v32] = a1;
    __syncthreads();
    if (g == 0) {
        float t0 = bias[0], t1 = bias[1];
        #pragma unroll
        for (int k = 0; k < 8; ++k) { t0 += r0[k][v32]; t1 += r1[k][v32]; }
        mask[p] = (t1 > t0) ? 1 : 0;
    }
}

// ---------------------------------------------------------------------------
// Per-voxel MLP prior + masked select, in-place over x ([128][N] f32)
__global__ __launch_bounds__(256) void mlp_vox(float* __restrict__ x,
                                               const float* __restrict__ w1,
                                               const float* __restrict__ b1,
                                               const float* __restrict__ g,
                                               const float* __restrict__ beta,
                                               const float* __restrict__ w2,
                                               const float* __restrict__ b2,
                                               const unsigned char* __restrict__ mask) {
    const int p = blockIdx.x * 256 + threadIdx.x;
    float h[64];
    #pragma unroll
    for (int j = 0; j < 64; ++j) h[j] = b1[j];
    #pragma unroll 1
    for (int c = 0; c < 128; ++c) {
        const float xv = x[(size_t)c * NVOX + p];
        #pragma unroll
        for (int j = 0; j < 64; ++j) h[j] = fmaf(xv, w1[c * 64 + j], h[j]);
    }
    float mu = 0.f;
    #pragma unroll
    for (int j = 0; j < 64; ++j) mu += h[j];
    mu *= (1.f / 64.f);
    float var = 0.f;
    #pragma unroll
    for (int j = 0; j < 64; ++j) { const float d = h[j] - mu; var = fmaf(d, d, var); }
    var *= (1.f / 64.f);
    const float rs = rsqrtf(var + 1e-5f);
    #pragma unroll
    for (int j = 0; j < 64; ++j) h[j] = leaky((h[j] - mu) * rs * g[j] + beta[j]);

    const bool m = mask[p] != 0;
    #pragma unroll 1
    for (int c = 0; c < 128; ++c) {
        float pr = b2[c];
        #pragma unroll
        for (int j = 0; j < 64; ++j) pr = fmaf(h[j], w2[j * 128 + c], pr);
        const size_t idx = (size_t)c * NVOX + p;
        x[idx] = m ? x[idx] : pr;
    }
}

// ---------------------------------------------------------------------------
extern "C" void kernel_launch(void* const* d_in, const int* in_sizes, int n_in,
                              void* d_out, int out_size, void* d_ws, size_t ws_size,
                              hipStream_t stream) {
    const float* x3d    = (const float*)d_in[0];
    const float* prob   = (const float*)d_in[1];
    const float* w_bot  = (const float*)d_in[2];
    const float* b_bot  = (const float*)d_in[3];
    const float* w_occ1 = (const float*)d_in[4];
    const float* b_occ1 = (const float*)d_in[5];
    const float* w_occ2 = (const float*)d_in[6];
    const float* b_occ2 = (const float*)d_in[7];
    const float* w_mlp1 = (const float*)d_in[8];
    const float* b_mlp1 = (const float*)d_in[9];
    const float* ln_g   = (const float*)d_in[10];
    const float* ln_b   = (const float*)d_in[11];
    const float* w_mlp2 = (const float*)d_in[12];
    const float* b_mlp2 = (const float*)d_in[13];
    const float* w_sdb  = (const float*)d_in[14];
    const float* b_sdb  = (const float*)d_in[15];
    const float* w_ssc  = (const float*)d_in[16];
    const float* b_ssc  = (const float*)d_in[17];

    char* ws = (char*)d_ws;
    float* X32 = (float*)(ws);                                 // [128][N] f32, 134.2 MB
    float* HR  = (float*)(ws + 134217728);                     // [64][3*SLAB] f32 ring, 25.2 MB
    unsigned short* WB3 = (unsigned short*)(ws + 159383552);   // 2654208 B
    unsigned short* W13 = (unsigned short*)(ws + 162037760);   // 1327104 B
    unsigned short* WS3 = (unsigned short*)(ws + 163364864);   // 1327104 B
    unsigned char* mask = (unsigned char*)(ws + 164691968);    // 262144 B

    const dim3 blk(256);

    wsplit3<<<1728, blk, 0, stream>>>(w_bot,  WB3, 128);
    wsplit3<<<864,  blk, 0, stream>>>(w_occ1, W13, 64);
    wsplit3<<<864,  blk, 0, stream>>>(w_sdb,  WS3, 64);

    // 1) bottleneck conv 128->128 (6-product) : x3d -> X32
    conv3s<128, 6, false, false, 0, false><<<4096, blk, 0, stream>>>(
        x3d, nullptr, WB3, b_bot, X32, nullptr, nullptr, 0);

    // 2/3) occ conv1 (premul folded, 6-product) per slab into ring; occ2 trails
    for (int s = 0; s < NSLAB; ++s) {
        conv3s<64, 6, true, true, 2, false><<<512, blk, 0, stream>>>(
            X32, prob, W13, b_occ1, HR, nullptr, nullptr, 16 * s);
        if (s >= 1) occ2p<<<1024, blk, 0, stream>>>(HR, w_occ2, b_occ2, mask, s - 1);
    }
    occ2p<<<1024, blk, 0, stream>>>(HR, w_occ2, b_occ2, mask, NSLAB - 1);

    // 4) MLP prior + masked select, in-place on X32
    mlp_vox<<<1024, blk, 0, stream>>>(X32, w_mlp1, b_mlp1, ln_g, ln_b, w_mlp2, b_mlp2, mask);

    // 5/6) SDB conv (3-product) + fused SSC head -> d_out [20][N] f32
    conv3s<64, 3, false, true, 0, true><<<4096, blk, 0, stream>>>(
        X32, nullptr, WS3, b_sdb, (float*)d_out, w_ssc, b_ssc, 0);
}